// Round 6
// baseline (274.516 us; speedup 1.0000x reference)
//
#include <hip/hip_runtime.h>

typedef __bf16 bf16;
typedef __bf16 bf16x2 __attribute__((ext_vector_type(2)));
typedef __bf16 bf16x4 __attribute__((ext_vector_type(4)));
typedef __bf16 bf16x8 __attribute__((ext_vector_type(8)));
typedef float f32x4 __attribute__((ext_vector_type(4)));

#define TSEQ 2048
#define NHEAD 16

// async global->LDS, 16B per lane (lane-linear dest, m97/m104)
__device__ __forceinline__ void gload_lds16(const bf16* g, bf16* s) {
  __builtin_amdgcn_global_load_lds(
      (const __attribute__((address_space(1))) void*)g,
      (__attribute__((address_space(3))) void*)s, 16, 0, 0);
}

// ---------------------------------------------------------------------------
// fp32 -> bf16 conversion, 8 elems/thread, vectorized
// ---------------------------------------------------------------------------
__global__ __launch_bounds__(256) void cvt_f32_bf16_kernel(
    const float* __restrict__ in, bf16* __restrict__ out) {
  size_t i = ((size_t)blockIdx.x * 256 + threadIdx.x) * 8;
  float4 v0 = ((const float4*)(in + i))[0];
  float4 v1 = ((const float4*)(in + i))[1];
  bf16x8 o;
  o[0] = (bf16)v0.x; o[1] = (bf16)v0.y; o[2] = (bf16)v0.z; o[3] = (bf16)v0.w;
  o[4] = (bf16)v1.x; o[5] = (bf16)v1.y; o[6] = (bf16)v1.z; o[7] = (bf16)v1.w;
  *(bf16x8*)(out + i) = o;
}

// ---------------------------------------------------------------------------
// transpose + convert: in (K x N) fp32 row-major -> out (N x K) bf16 row-major
// ---------------------------------------------------------------------------
__global__ __launch_bounds__(256) void transpose_cvt_kernel(
    const float* __restrict__ in, bf16* __restrict__ out, int K, int N) {
  __shared__ float tile[32][33];
  int n0 = blockIdx.x * 32, k0 = blockIdx.y * 32;
  int tx = threadIdx.x & 31, ty = threadIdx.x >> 5;
#pragma unroll
  for (int i = ty; i < 32; i += 8)
    tile[i][tx] = in[(size_t)(k0 + i) * N + n0 + tx];
  __syncthreads();
#pragma unroll
  for (int i = ty; i < 32; i += 8)
    out[(size_t)(n0 + i) * K + k0 + tx] = (bf16)tile[tx][i];
}

// ---------------------------------------------------------------------------
// GEMM: C(MxN) = A(MxK) @ Bt(NxK)^T + bias. 128x128 tile, BK=32, m97-style
// global_load_lds width-16 staging with XOR-swizzled k-chunk layout:
// 16B chunk for (row r, kchunk j) lives at LDS chunk r*4 + (j ^ ((r>>1)&3)).
// Swizzle is applied on the GLOBAL source address (stays within one 64B line,
// coalescing intact); LDS dests remain lane-linear as global_load_lds needs.
// Fragment reads then span all 8 bank-groups (2 lanes each) -> conflict-free
// (was 8-way, 6.3M conflicts/dispatch). Columns gc < scale_cols get *0.125.
// ---------------------------------------------------------------------------
template <typename OutT>
__global__ __launch_bounds__(256, 4) void gemm_bf16_kernel(
    const bf16* __restrict__ A, const bf16* __restrict__ Bt,
    const float* __restrict__ bias, OutT* __restrict__ C,
    int M, int N, int K, int scale_cols) {
  alignas(16) __shared__ bf16 As[128 * 32];
  alignas(16) __shared__ bf16 Bs[128 * 32];
  const int row0 = blockIdx.y * 128, col0 = blockIdx.x * 128;
  const int tid = threadIdx.x;
  const int wave = tid >> 6, lane = tid & 63;
  const int quad = lane >> 4, lm = lane & 15;
  const int wm = (wave >> 1) * 64, wn = (wave & 1) * 64;

  f32x4 acc[4][4];
  const f32x4 z4 = {0.0f, 0.0f, 0.0f, 0.0f};
#pragma unroll
  for (int i = 0; i < 4; i++)
#pragma unroll
    for (int j = 0; j < 4; j++) acc[i][j] = z4;

  // staging: thread t owns LDS chunks t and t+256. Chunk t = (row sr, kchunk
  // js) with sr = t>>2, js = (t&3) ^ ((sr>>1)&3). Row sr+64 has the same
  // swizzle term (64>>1 & 3 == 0).
  const int sr = tid >> 2;
  const int js = (tid & 3) ^ ((sr >> 1) & 3);
  const bf16* apg = A + (size_t)(row0 + sr) * K + js * 8;
  const bf16* bpg = Bt + (size_t)(col0 + sr) * K + js * 8;
  const size_t half = (size_t)64 * K;

  // fragment-read swizzle: rows are wm/wn + i*16 + lm; multiples of 16
  // contribute 0 to (row>>1)&3, so sw depends only on lm.
  const int sw = (lm >> 1) & 3;
  const int kcA = (quad ^ sw) * 8;

  for (int k0 = 0; k0 < K; k0 += 32) {
    __syncthreads();
    gload_lds16(apg, &As[tid * 8]);
    gload_lds16(apg + half, &As[(256 + tid) * 8]);
    gload_lds16(bpg, &Bs[tid * 8]);
    gload_lds16(bpg + half, &Bs[(256 + tid) * 8]);
    apg += 32; bpg += 32;
    __syncthreads();

    bf16x8 af[4], bfr[4];
#pragma unroll
    for (int i = 0; i < 4; i++)
      af[i] = *(const bf16x8*)&As[(wm + i * 16 + lm) * 32 + kcA];
#pragma unroll
    for (int j = 0; j < 4; j++)
      bfr[j] = *(const bf16x8*)&Bs[(wn + j * 16 + lm) * 32 + kcA];
#pragma unroll
    for (int i = 0; i < 4; i++)
#pragma unroll
      for (int j = 0; j < 4; j++)
        acc[i][j] = __builtin_amdgcn_mfma_f32_16x16x32_bf16(af[i], bfr[j], acc[i][j], 0, 0, 0);
  }

#pragma unroll
  for (int j = 0; j < 4; j++) {
    int gc = col0 + wn + j * 16 + lm;
    float bb = bias[gc];
    float sc2 = (gc < scale_cols) ? 0.125f : 1.0f;
#pragma unroll
    for (int i = 0; i < 4; i++) {
      int gr = row0 + wm + i * 16 + quad * 4;
#pragma unroll
      for (int rr = 0; rr < 4; rr++) {
        float v = (acc[i][j][rr] + bb) * sc2;
        C[(size_t)(gr + rr) * N + gc] = (OutT)v;
      }
    }
  }
}

// ---------------------------------------------------------------------------
// V transpose per head: qkv V-part -> vp[(b*16+h)*64 + d][t]. 64x64 tiles,
// bf16x2 (4B/lane) global accesses both directions.
// ---------------------------------------------------------------------------
__global__ __launch_bounds__(256) void transpose_v_kernel(
    const bf16* __restrict__ qkv, bf16* __restrict__ vp) {
  __shared__ bf16 tile[64][65];
  int bh = blockIdx.y, b = bh >> 4, h = bh & 15;
  int t0 = blockIdx.x * 64;
  int tx = threadIdx.x & 31, ty = threadIdx.x >> 5;
#pragma unroll
  for (int i = ty; i < 64; i += 8) {
    bf16x2 v = *(const bf16x2*)&qkv[(size_t)(b * TSEQ + t0 + i) * 3072 + 2048 + h * 64 + 2 * tx];
    tile[i][2 * tx] = v[0];
    tile[i][2 * tx + 1] = v[1];
  }
  __syncthreads();
#pragma unroll
  for (int i = ty; i < 64; i += 8) {
    bf16x2 v;
    v[0] = tile[2 * tx][i];
    v[1] = tile[2 * tx + 1][i];
    *(bf16x2*)&vp[(size_t)(bh * 64 + i) * TSEQ + t0 + 2 * tx] = v;
  }
}

// ---------------------------------------------------------------------------
// Flash attention, fixed-shift softmax (scores*0.125 ~ N(0,1); overflow would
// need ~88 sigma). S^T = K*Q^T, O^T = V^T*P^T; per-lane l partials reduced
// once per q-tile. Q pre-scaled by 0.125 in the QKV GEMM. Grid (64 hb, 16 y),
// qt = 15-y; hb in x keeps each (h,b)'s blocks on one XCD. 4 blocks/CU.
// ---------------------------------------------------------------------------
__global__ __launch_bounds__(256, 4) void flash_attn_kernel(
    const bf16* __restrict__ qkv, const bf16* __restrict__ vp,
    bf16* __restrict__ att) {
  alignas(16) __shared__ bf16 Ks[64 * 72];
  alignas(16) __shared__ bf16 Vts[64 * 72];
  alignas(16) __shared__ bf16 Ps[4][32 * 72];

  const int hb = blockIdx.x;
  const int h = hb & 15, b = hb >> 4;
  const int qt = 15 - blockIdx.y;
  const int q0 = qt * 128;
  const int tid = threadIdx.x;
  const int wave = tid >> 6, lane = tid & 63;
  const int quad = lane >> 4, lm = lane & 15;
  const size_t rowbase = (size_t)b * TSEQ;
  const f32x4 z4 = {0.0f, 0.0f, 0.0f, 0.0f};

  bf16x8 bq[2][2];
#pragma unroll
  for (int nf = 0; nf < 2; nf++)
#pragma unroll
    for (int ks = 0; ks < 2; ks++)
      bq[nf][ks] = *(const bf16x8*)(qkv +
          (rowbase + q0 + wave * 32 + nf * 16 + lm) * 3072 + h * 64 + ks * 32 + quad * 8);

  f32x4 oT[4][2];
#pragma unroll
  for (int mf = 0; mf < 4; mf++)
#pragma unroll
    for (int nf = 0; nf < 2; nf++) oT[mf][nf] = z4;
  float lp[2] = {0.0f, 0.0f};

  const int nkt = 2 * qt + 2;
  const int wrow_lo = q0 + wave * 32;
  const int wrow_hi = wrow_lo + 31;

  for (int kt = 0; kt < nkt; kt++) {
    const int k0 = kt * 64;
    __syncthreads();
    {
      int rr = tid >> 2, c0 = (tid & 3) * 16;
      const float4* ksrc = (const float4*)(qkv + (rowbase + k0 + rr) * 3072 + 1024 + h * 64 + c0);
      float4 ka = ksrc[0], kb = ksrc[1];
      const float4* vsrc = (const float4*)(vp + ((size_t)(b * NHEAD + h) * 64 + rr) * TSEQ + k0 + c0);
      float4 v0 = vsrc[0], v1 = vsrc[1];
      float4* kd = (float4*)&Ks[rr * 72 + c0];
      kd[0] = ka; kd[1] = kb;
      float4* vd = (float4*)&Vts[rr * 72 + c0];
      vd[0] = v0; vd[1] = v1;
    }
    __syncthreads();
    if (k0 > wrow_hi) continue;

    // ---- S^T = K Q^T ----
    f32x4 s[4][2];
#pragma unroll
    for (int mf = 0; mf < 4; mf++)
#pragma unroll
      for (int nf = 0; nf < 2; nf++) s[mf][nf] = z4;
#pragma unroll
    for (int ks = 0; ks < 2; ks++) {
      bf16x8 ak[4];
#pragma unroll
      for (int mf = 0; mf < 4; mf++)
        ak[mf] = *(const bf16x8*)&Ks[(mf * 16 + lm) * 72 + ks * 32 + quad * 8];
#pragma unroll
      for (int mf = 0; mf < 4; mf++)
#pragma unroll
        for (int nf = 0; nf < 2; nf++)
          s[mf][nf] = __builtin_amdgcn_mfma_f32_16x16x32_bf16(ak[mf], bq[nf][ks], s[mf][nf], 0, 0, 0);
    }

    // ---- P = exp(S^T); mask only on diagonal tiles ----
    const bool need_mask = (k0 + 63 > wrow_lo);
#pragma unroll
    for (int nf = 0; nf < 2; nf++) {
      const int qrow = q0 + wave * 32 + nf * 16 + lm;
#pragma unroll
      for (int mf = 0; mf < 4; mf++) {
        bf16x4 pk;
        float psum = 0.0f;
#pragma unroll
        for (int rr = 0; rr < 4; rr++) {
          float pv = __expf(s[mf][nf][rr]);
          if (need_mask) {
            int kv = k0 + mf * 16 + quad * 4 + rr;
            pv = (kv > qrow) ? 0.0f : pv;
          }
          psum += pv;
          pk[rr] = (bf16)pv;
        }
        lp[nf] += psum;
        *(bf16x4*)&Ps[wave][(nf * 16 + lm) * 72 + mf * 16 + quad * 4] = pk;
      }
    }

    // ---- O^T += V^T P^T ----
#pragma unroll
    for (int ks = 0; ks < 2; ks++) {
      bf16x8 av[4], bp[2];
#pragma unroll
      for (int mf = 0; mf < 4; mf++)
        av[mf] = *(const bf16x8*)&Vts[(mf * 16 + lm) * 72 + ks * 32 + quad * 8];
#pragma unroll
      for (int nf = 0; nf < 2; nf++)
        bp[nf] = *(const bf16x8*)&Ps[wave][(nf * 16 + lm) * 72 + ks * 32 + quad * 8];
#pragma unroll
      for (int mf = 0; mf < 4; mf++)
#pragma unroll
        for (int nf = 0; nf < 2; nf++)
          oT[mf][nf] = __builtin_amdgcn_mfma_f32_16x16x32_bf16(av[mf], bp[nf], oT[mf][nf], 0, 0, 0);
    }
  }

  float linv[2];
#pragma unroll
  for (int nf = 0; nf < 2; nf++) {
    float l = lp[nf];
    l += __shfl_xor(l, 16, 64);
    l += __shfl_xor(l, 32, 64);
    linv[nf] = 1.0f / l;
  }

#pragma unroll
  for (int nf = 0; nf < 2; nf++) {
    const size_t grow = rowbase + q0 + wave * 32 + nf * 16 + lm;
#pragma unroll
    for (int mf = 0; mf < 4; mf++) {
      bf16x4 ok;
#pragma unroll
      for (int rr = 0; rr < 4; rr++) ok[rr] = (bf16)(oT[mf][nf][rr] * linv[nf]);
      *(bf16x4*)(att + grow * 1024 + h * 64 + mf * 16 + quad * 4) = ok;
    }
  }
}

extern "C" void kernel_launch(void* const* d_in, const int* in_sizes, int n_in,
                              void* d_out, int out_size, void* d_ws, size_t ws_size,
                              hipStream_t stream) {
  const float* x = (const float*)d_in[0];
  const float* w_qkv = (const float*)d_in[1];
  const float* b_qkv = (const float*)d_in[2];
  const float* w_out = (const float*)d_in[3];
  const float* b_out = (const float*)d_in[4];
  float* out = (float*)d_out;

  char* ws = (char*)d_ws;
  bf16* Xbf   = (bf16*)(ws);                 // 8192x1024
  bf16* Wqkvt = (bf16*)(ws + 16777216);      // 3072x1024
  bf16* Woutt = (bf16*)(ws + 23068672);      // 1024x1024
  bf16* QKV   = (bf16*)(ws + 25165824);      // 8192x3072 (Q part pre-scaled by 0.125)
  bf16* VP    = (bf16*)(ws + 75497472);      // 64*64x2048
  bf16* ATT   = (bf16*)(ws + 92274688);      // 8192x1024

  cvt_f32_bf16_kernel<<<4096, 256, 0, stream>>>(x, Xbf);
  transpose_cvt_kernel<<<dim3(96, 32), 256, 0, stream>>>(w_qkv, Wqkvt, 1024, 3072);
  transpose_cvt_kernel<<<dim3(32, 32), 256, 0, stream>>>(w_out, Woutt, 1024, 1024);
  gemm_bf16_kernel<bf16><<<dim3(24, 64), 256, 0, stream>>>(Xbf, Wqkvt, b_qkv, QKV, 8192, 3072, 1024, 1024);
  transpose_v_kernel<<<dim3(32, 64), 256, 0, stream>>>(QKV, VP);
  flash_attn_kernel<<<dim3(64, 16, 1), 256, 0, stream>>>(QKV, VP, ATT);
  gemm_bf16_kernel<float><<<dim3(8, 64), 256, 0, stream>>>(ATT, Woutt, b_out, out, 8192, 1024, 1024, 0);
}

// Round 7
// 251.087 us; speedup vs baseline: 1.0933x; 1.0933x over previous
//
#include <hip/hip_runtime.h>

typedef __bf16 bf16;
typedef __bf16 bf16x4 __attribute__((ext_vector_type(4)));
typedef __bf16 bf16x8 __attribute__((ext_vector_type(8)));
typedef float f32x4 __attribute__((ext_vector_type(4)));

#define TSEQ 2048
#define NHEAD 16

// async global->LDS, 16B per lane (lane-linear dest, m97/m104)
__device__ __forceinline__ void gload_lds16(const bf16* g, bf16* s) {
  __builtin_amdgcn_global_load_lds(
      (const __attribute__((address_space(1))) void*)g,
      (__attribute__((address_space(3))) void*)s, 16, 0, 0);
}

// ---------------------------------------------------------------------------
// Fused prep: [0,4096) x fp32->bf16; [4096,7168) w_qkv T+cvt; [7168,8192)
// w_out T+cvt. One dispatch instead of three (graph-gap reduction).
// ---------------------------------------------------------------------------
__global__ __launch_bounds__(256) void prep_kernel(
    const float* __restrict__ x, bf16* __restrict__ xbf,
    const float* __restrict__ w_qkv, bf16* __restrict__ wqkvt,
    const float* __restrict__ w_out, bf16* __restrict__ woutt) {
  __shared__ float tile[32][33];
  const int bid = blockIdx.x;
  const int tid = threadIdx.x;
  if (bid < 4096) {
    size_t i = ((size_t)bid * 256 + tid) * 8;
    float4 v0 = ((const float4*)(x + i))[0];
    float4 v1 = ((const float4*)(x + i))[1];
    bf16x8 o;
    o[0] = (bf16)v0.x; o[1] = (bf16)v0.y; o[2] = (bf16)v0.z; o[3] = (bf16)v0.w;
    o[4] = (bf16)v1.x; o[5] = (bf16)v1.y; o[6] = (bf16)v1.z; o[7] = (bf16)v1.w;
    *(bf16x8*)(xbf + i) = o;
    return;
  }
  const float* in; bf16* out; int K, N, n0, k0;
  if (bid < 7168) {
    int q = bid - 4096;
    in = w_qkv; out = wqkvt; K = 1024; N = 3072;
    n0 = (q % 96) * 32; k0 = (q / 96) * 32;
  } else {
    int q = bid - 7168;
    in = w_out; out = woutt; K = 1024; N = 1024;
    n0 = (q & 31) * 32; k0 = (q >> 5) * 32;
  }
  int tx = tid & 31, ty = tid >> 5;
#pragma unroll
  for (int i = ty; i < 32; i += 8)
    tile[i][tx] = in[(size_t)(k0 + i) * N + n0 + tx];
  __syncthreads();
#pragma unroll
  for (int i = ty; i < 32; i += 8)
    out[(size_t)(n0 + i) * K + k0 + tx] = (bf16)tile[tx][i];
}

// ---------------------------------------------------------------------------
// GEMM: C(MxN) = A(MxK) @ Bt(NxK)^T + bias. 128x128 tile, BK=64 (2 MFMA
// k-steps per barrier pair -- halves barrier-drain count vs BK=32).
// global_load_lds width-16 staging, XOR-swizzled k-chunks: chunk (row r,
// kchunk j) lives at LDS chunk r*8 + (j ^ ((r>>1)&7)); swizzle applied on
// the GLOBAL source address (within one 128B row span), LDS dests stay
// lane-linear. Fragment reads span all 8 bank-groups -> conflict-free.
// Columns gc < scale_cols get *0.125 (pre-scales Q for attention).
// If vp != null, columns gc >= 2048 (the V part of QKV) are written
// TRANSPOSED to vp[(b*1024 + gc-2048)*2048 + t] instead of C: the 4 rr acc
// values are 4 consecutive t -> one bf16x4 store. Kills the separate
// V-transpose kernel and QKV's V-region writes.
// ---------------------------------------------------------------------------
template <typename OutT>
__global__ __launch_bounds__(256, 4) void gemm_bf16_kernel(
    const bf16* __restrict__ A, const bf16* __restrict__ Bt,
    const float* __restrict__ bias, OutT* __restrict__ C,
    int M, int N, int K, int scale_cols, bf16* __restrict__ vp) {
  alignas(16) __shared__ bf16 As[128 * 64];
  alignas(16) __shared__ bf16 Bs[128 * 64];
  const int row0 = blockIdx.y * 128, col0 = blockIdx.x * 128;
  const int tid = threadIdx.x;
  const int wave = tid >> 6, lane = tid & 63;
  const int quad = lane >> 4, lm = lane & 15;
  const int wm = (wave >> 1) * 64, wn = (wave & 1) * 64;

  f32x4 acc[4][4];
  const f32x4 z4 = {0.0f, 0.0f, 0.0f, 0.0f};
#pragma unroll
  for (int i = 0; i < 4; i++)
#pragma unroll
    for (int j = 0; j < 4; j++) acc[i][j] = z4;

  // staging: 1024 chunks (128 rows x 8 kchunks) per matrix; thread t owns
  // chunks t, t+256, t+512, t+768 (rows sr0+{0,32,64,96}, same swizzled js
  // since 32-row steps leave (sr>>1)&7 unchanged).
  const int sr0 = tid >> 3;
  const int js = (tid & 7) ^ ((tid >> 4) & 7);
  const bf16* apg = A + (size_t)(row0 + sr0) * K + js * 8;
  const bf16* bpg = Bt + (size_t)(col0 + sr0) * K + js * 8;
  const size_t row32 = (size_t)32 * K;

  // fragment swizzle: rows are 16m+lm -> (row>>1)&7 == (lm>>1)&7
  const int sw = (lm >> 1) & 7;

  for (int k0 = 0; k0 < K; k0 += 64) {
    __syncthreads();
#pragma unroll
    for (int p = 0; p < 4; p++) {
      gload_lds16(apg + p * row32, &As[(p * 256 + tid) * 8]);
      gload_lds16(bpg + p * row32, &Bs[(p * 256 + tid) * 8]);
    }
    apg += 64; bpg += 64;
    __syncthreads();

#pragma unroll
    for (int ks = 0; ks < 2; ks++) {
      const int kc = ((ks * 4 + quad) ^ sw) * 8;
      bf16x8 af[4], bfr[4];
#pragma unroll
      for (int i = 0; i < 4; i++)
        af[i] = *(const bf16x8*)&As[(wm + i * 16 + lm) * 64 + kc];
#pragma unroll
      for (int j = 0; j < 4; j++)
        bfr[j] = *(const bf16x8*)&Bs[(wn + j * 16 + lm) * 64 + kc];
#pragma unroll
      for (int i = 0; i < 4; i++)
#pragma unroll
        for (int j = 0; j < 4; j++)
          acc[i][j] = __builtin_amdgcn_mfma_f32_16x16x32_bf16(af[i], bfr[j], acc[i][j], 0, 0, 0);
    }
  }

#pragma unroll
  for (int j = 0; j < 4; j++) {
    int gc = col0 + wn + j * 16 + lm;
    float bb = bias[gc];
    float sc2 = (gc < scale_cols) ? 0.125f : 1.0f;
    if (vp != nullptr && gc >= 2048) {
      // V part -> transposed vp; rows of one 128-tile share one b.
      int gr0 = row0 + wm + quad * 4;
      int b = gr0 >> 11;
      size_t vrow = (size_t)(b * 1024 + gc - 2048) * TSEQ;
#pragma unroll
      for (int i = 0; i < 4; i++) {
        int t = (gr0 + i * 16) & (TSEQ - 1);
        bf16x4 vk;
#pragma unroll
        for (int rr = 0; rr < 4; rr++) vk[rr] = (bf16)(acc[i][j][rr] + bb);
        *(bf16x4*)(vp + vrow + t) = vk;
      }
    } else {
#pragma unroll
      for (int i = 0; i < 4; i++) {
        int gr = row0 + wm + i * 16 + quad * 4;
#pragma unroll
        for (int rr = 0; rr < 4; rr++) {
          float v = (acc[i][j][rr] + bb) * sc2;
          C[(size_t)(gr + rr) * N + gc] = (OutT)v;
        }
      }
    }
  }
}

// ---------------------------------------------------------------------------
// Flash attention, fixed-shift softmax (scores*0.125 ~ N(0,1); overflow would
// need ~88 sigma). S^T = K*Q^T, O^T = V^T*P^T; per-lane l partials reduced
// once per q-tile. Q pre-scaled by 0.125 in the QKV GEMM. Grid (64 hb, 16 y),
// qt = 15-y; hb in x keeps each (h,b)'s blocks on one XCD. 4 blocks/CU.
// ---------------------------------------------------------------------------
__global__ __launch_bounds__(256, 4) void flash_attn_kernel(
    const bf16* __restrict__ qkv, const bf16* __restrict__ vp,
    bf16* __restrict__ att) {
  alignas(16) __shared__ bf16 Ks[64 * 72];
  alignas(16) __shared__ bf16 Vts[64 * 72];
  alignas(16) __shared__ bf16 Ps[4][32 * 72];

  const int hb = blockIdx.x;
  const int h = hb & 15, b = hb >> 4;
  const int qt = 15 - blockIdx.y;
  const int q0 = qt * 128;
  const int tid = threadIdx.x;
  const int wave = tid >> 6, lane = tid & 63;
  const int quad = lane >> 4, lm = lane & 15;
  const size_t rowbase = (size_t)b * TSEQ;
  const f32x4 z4 = {0.0f, 0.0f, 0.0f, 0.0f};

  bf16x8 bq[2][2];
#pragma unroll
  for (int nf = 0; nf < 2; nf++)
#pragma unroll
    for (int ks = 0; ks < 2; ks++)
      bq[nf][ks] = *(const bf16x8*)(qkv +
          (rowbase + q0 + wave * 32 + nf * 16 + lm) * 3072 + h * 64 + ks * 32 + quad * 8);

  f32x4 oT[4][2];
#pragma unroll
  for (int mf = 0; mf < 4; mf++)
#pragma unroll
    for (int nf = 0; nf < 2; nf++) oT[mf][nf] = z4;
  float lp[2] = {0.0f, 0.0f};

  const int nkt = 2 * qt + 2;
  const int wrow_lo = q0 + wave * 32;
  const int wrow_hi = wrow_lo + 31;

  for (int kt = 0; kt < nkt; kt++) {
    const int k0 = kt * 64;
    __syncthreads();
    {
      int rr = tid >> 2, c0 = (tid & 3) * 16;
      const float4* ksrc = (const float4*)(qkv + (rowbase + k0 + rr) * 3072 + 1024 + h * 64 + c0);
      float4 ka = ksrc[0], kb = ksrc[1];
      const float4* vsrc = (const float4*)(vp + ((size_t)(b * NHEAD + h) * 64 + rr) * TSEQ + k0 + c0);
      float4 v0 = vsrc[0], v1 = vsrc[1];
      float4* kd = (float4*)&Ks[rr * 72 + c0];
      kd[0] = ka; kd[1] = kb;
      float4* vd = (float4*)&Vts[rr * 72 + c0];
      vd[0] = v0; vd[1] = v1;
    }
    __syncthreads();
    if (k0 > wrow_hi) continue;

    // ---- S^T = K Q^T ----
    f32x4 s[4][2];
#pragma unroll
    for (int mf = 0; mf < 4; mf++)
#pragma unroll
      for (int nf = 0; nf < 2; nf++) s[mf][nf] = z4;
#pragma unroll
    for (int ks = 0; ks < 2; ks++) {
      bf16x8 ak[4];
#pragma unroll
      for (int mf = 0; mf < 4; mf++)
        ak[mf] = *(const bf16x8*)&Ks[(mf * 16 + lm) * 72 + ks * 32 + quad * 8];
#pragma unroll
      for (int mf = 0; mf < 4; mf++)
#pragma unroll
        for (int nf = 0; nf < 2; nf++)
          s[mf][nf] = __builtin_amdgcn_mfma_f32_16x16x32_bf16(ak[mf], bq[nf][ks], s[mf][nf], 0, 0, 0);
    }

    // ---- P = exp(S^T); mask only on diagonal tiles ----
    const bool need_mask = (k0 + 63 > wrow_lo);
#pragma unroll
    for (int nf = 0; nf < 2; nf++) {
      const int qrow = q0 + wave * 32 + nf * 16 + lm;
#pragma unroll
      for (int mf = 0; mf < 4; mf++) {
        bf16x4 pk;
        float psum = 0.0f;
#pragma unroll
        for (int rr = 0; rr < 4; rr++) {
          float pv = __expf(s[mf][nf][rr]);
          if (need_mask) {
            int kv = k0 + mf * 16 + quad * 4 + rr;
            pv = (kv > qrow) ? 0.0f : pv;
          }
          psum += pv;
          pk[rr] = (bf16)pv;
        }
        lp[nf] += psum;
        *(bf16x4*)&Ps[wave][(nf * 16 + lm) * 72 + mf * 16 + quad * 4] = pk;
      }
    }

    // ---- O^T += V^T P^T ----
#pragma unroll
    for (int ks = 0; ks < 2; ks++) {
      bf16x8 av[4], bp[2];
#pragma unroll
      for (int mf = 0; mf < 4; mf++)
        av[mf] = *(const bf16x8*)&Vts[(mf * 16 + lm) * 72 + ks * 32 + quad * 8];
#pragma unroll
      for (int nf = 0; nf < 2; nf++)
        bp[nf] = *(const bf16x8*)&Ps[wave][(nf * 16 + lm) * 72 + ks * 32 + quad * 8];
#pragma unroll
      for (int mf = 0; mf < 4; mf++)
#pragma unroll
        for (int nf = 0; nf < 2; nf++)
          oT[mf][nf] = __builtin_amdgcn_mfma_f32_16x16x32_bf16(av[mf], bp[nf], oT[mf][nf], 0, 0, 0);
    }
  }

  float linv[2];
#pragma unroll
  for (int nf = 0; nf < 2; nf++) {
    float l = lp[nf];
    l += __shfl_xor(l, 16, 64);
    l += __shfl_xor(l, 32, 64);
    linv[nf] = 1.0f / l;
  }

#pragma unroll
  for (int nf = 0; nf < 2; nf++) {
    const size_t grow = rowbase + q0 + wave * 32 + nf * 16 + lm;
#pragma unroll
    for (int mf = 0; mf < 4; mf++) {
      bf16x4 ok;
#pragma unroll
      for (int rr = 0; rr < 4; rr++) ok[rr] = (bf16)(oT[mf][nf][rr] * linv[nf]);
      *(bf16x4*)(att + grow * 1024 + h * 64 + mf * 16 + quad * 4) = ok;
    }
  }
}

extern "C" void kernel_launch(void* const* d_in, const int* in_sizes, int n_in,
                              void* d_out, int out_size, void* d_ws, size_t ws_size,
                              hipStream_t stream) {
  const float* x = (const float*)d_in[0];
  const float* w_qkv = (const float*)d_in[1];
  const float* b_qkv = (const float*)d_in[2];
  const float* w_out = (const float*)d_in[3];
  const float* b_out = (const float*)d_in[4];
  float* out = (float*)d_out;

  char* ws = (char*)d_ws;
  bf16* Xbf   = (bf16*)(ws);                 // 8192x1024
  bf16* Wqkvt = (bf16*)(ws + 16777216);      // 3072x1024
  bf16* Woutt = (bf16*)(ws + 23068672);      // 1024x1024
  bf16* QKV   = (bf16*)(ws + 25165824);      // 8192x3072 (Q pre-scaled; V region unused)
  bf16* VP    = (bf16*)(ws + 75497472);      // [b*1024 + h*64+d][t]
  bf16* ATT   = (bf16*)(ws + 92274688);      // 8192x1024

  prep_kernel<<<8192, 256, 0, stream>>>(x, Xbf, w_qkv, Wqkvt, w_out, Woutt);
  gemm_bf16_kernel<bf16><<<dim3(24, 64), 256, 0, stream>>>(
      Xbf, Wqkvt, b_qkv, QKV, 8192, 3072, 1024, 1024, VP);
  flash_attn_kernel<<<dim3(64, 16, 1), 256, 0, stream>>>(QKV, VP, ATT);
  gemm_bf16_kernel<float><<<dim3(8, 64), 256, 0, stream>>>(
      ATT, Woutt, b_out, out, 8192, 1024, 1024, 0, nullptr);
}